// Round 2
// baseline (2196.170 us; speedup 1.0000x reference)
//
#include <hip/hip_runtime.h>

namespace {

constexpr int B      = 512;   // batch rows
constexpr int IN_F   = 784;
constexpr int E      = 512;
constexpr int T      = 64;    // num blocks
constexpr int ABSZ   = 16;    // A * BSZ
constexpr int J      = 7;
constexpr int NC     = 128;
constexpr int TILE_R = 8;     // rows per matvec tile
constexpr int MAXTIL = 128;   // >= max sum ceil(G_b/8) = 120

// ---------------------------------------------------------------------------
// identity descriptors (for stages whose weights are shared across all rows)
__global__ void k_iddesc(int* __restrict__ rows_id, int4* __restrict__ desc_id)
{
    const int t = threadIdx.x;  // NT = 512
    rows_id[t] = t;
    if (t < MAXTIL)
        desc_id[t] = (t < B / TILE_R) ? make_int4(0, t * TILE_R, TILE_R, 0)
                                      : make_int4(0, 0, 0, 0);
}

// ---------------------------------------------------------------------------
// embedding: state = init = x @ emb_W + emb_b     grid (64, 2), NT=256
__global__ __launch_bounds__(256) void k_embed(
    const float* __restrict__ x, const float* __restrict__ Wm,
    const float* __restrict__ bias,
    float* __restrict__ state, float* __restrict__ initv)
{
    const int c  = blockIdx.y * 256 + threadIdx.x;
    const int r0 = blockIdx.x * 8;
    float acc[8] = {0,0,0,0,0,0,0,0};
    const float* Wb = Wm + c;
    for (int e = 0; e < IN_F; e += 4) {
        const float w0 = Wb[(size_t)(e + 0) * E];
        const float w1 = Wb[(size_t)(e + 1) * E];
        const float w2 = Wb[(size_t)(e + 2) * E];
        const float w3 = Wb[(size_t)(e + 3) * E];
        #pragma unroll
        for (int g = 0; g < 8; ++g) {
            const float4 xv = *reinterpret_cast<const float4*>(
                x + (size_t)(r0 + g) * IN_F + e);
            acc[g] = fmaf(xv.x, w0, acc[g]);
            acc[g] = fmaf(xv.y, w1, acc[g]);
            acc[g] = fmaf(xv.z, w2, acc[g]);
            acc[g] = fmaf(xv.w, w3, acc[g]);
        }
    }
    const float bv = bias[c];
    #pragma unroll
    for (int g = 0; g < 8; ++g) {
        const float v = acc[g] + bv;
        state[(size_t)(r0 + g) * E + c] = v;
        initv[(size_t)(r0 + g) * E + c] = v;
    }
}

// ---------------------------------------------------------------------------
// norms[row] = ||state[row]||          grid 512, NT=64
__global__ __launch_bounds__(64) void k_norm(const float* __restrict__ state,
                                             float* __restrict__ norms)
{
    const int row = blockIdx.x;
    const int t   = threadIdx.x;
    const float4 a = *reinterpret_cast<const float4*>(state + (size_t)row * E + t * 8);
    const float4 b = *reinterpret_cast<const float4*>(state + (size_t)row * E + t * 8 + 4);
    float ss = a.x*a.x + a.y*a.y + a.z*a.z + a.w*a.w
             + b.x*b.x + b.y*b.y + b.z*b.z + b.w*b.w;
    #pragma unroll
    for (int off = 32; off > 0; off >>= 1) ss += __shfl_down(ss, off, 64);
    if (t == 0) norms[row] = sqrtf(ss);
}

// ---------------------------------------------------------------------------
// bucket rows by idx -> rows_sorted + tile descriptors   grid 1, NT=512
__global__ __launch_bounds__(512) void k_bucket(const int* __restrict__ idx,
                                                int* __restrict__ rows_sorted,
                                                int4* __restrict__ desc)
{
    __shared__ int cnt[T], off[T], c2[T];
    const int t = threadIdx.x;
    if (t < T) { cnt[t] = 0; c2[t] = 0; }
    __syncthreads();
    const int my = idx[t];
    atomicAdd(&cnt[my], 1);
    __syncthreads();
    if (t == 0) {
        int s = 0;
        for (int b = 0; b < T; ++b) { off[b] = s; s += cnt[b]; }
    }
    __syncthreads();
    const int p = off[my] + atomicAdd(&c2[my], 1);
    rows_sorted[p] = t;
    if (t == 0) {
        int slot = 0;
        for (int b = 0; b < T; ++b) {
            const int G = cnt[b], o = off[b];
            for (int k = 0; k < G; k += TILE_R)
                desc[slot++] = make_int4(b, o + k, min(TILE_R, G - k), 0);
        }
        for (; slot < MAXTIL; ++slot) desc[slot] = make_int4(0, 0, 0, 0);
    }
}

// ---------------------------------------------------------------------------
// grouped matvec: out[row] = epilogue(in[row] @ W[blk] + bias[blk])
// grid (MAXTIL, 2), NT=256, thread owns one output column.
template <bool RELU, bool SCALE, bool ADDINIT>
__global__ __launch_bounds__(256) void k_mv(
    const float* __restrict__ in, float* __restrict__ out,
    const float* __restrict__ W, const float* __restrict__ bias,
    const int4* __restrict__ desc, const int* __restrict__ rows,
    const float* __restrict__ norms, const float* __restrict__ initv)
{
    const int4 d = desc[blockIdx.x];
    const int n = d.z;
    if (n == 0) return;
    const int blk = d.x, start = d.y;
    const int c = blockIdx.y * 256 + threadIdx.x;
    const float* Wb = W + (size_t)blk * E * E + c;

    int rowid[TILE_R];
    int rbase[TILE_R];
    #pragma unroll
    for (int g = 0; g < TILE_R; ++g) {
        rowid[g] = rows[start + min(g, n - 1)];
        rbase[g] = rowid[g] * E;
    }

    float acc[TILE_R] = {0,0,0,0,0,0,0,0};
    for (int e = 0; e < E; e += 4) {
        const float w0 = Wb[(size_t)(e + 0) * E];
        const float w1 = Wb[(size_t)(e + 1) * E];
        const float w2 = Wb[(size_t)(e + 2) * E];
        const float w3 = Wb[(size_t)(e + 3) * E];
        #pragma unroll
        for (int g = 0; g < TILE_R; ++g) {
            const float4 sv = *reinterpret_cast<const float4*>(in + rbase[g] + e);
            acc[g] = fmaf(sv.x, w0, acc[g]);
            acc[g] = fmaf(sv.y, w1, acc[g]);
            acc[g] = fmaf(sv.z, w2, acc[g]);
            acc[g] = fmaf(sv.w, w3, acc[g]);
        }
    }

    const float bv = bias[blk * E + c];
    #pragma unroll
    for (int g = 0; g < TILE_R; ++g) {
        if (g < n) {
            float v = acc[g] + bv;
            if (RELU) v = fmaxf(v, 0.f);
            if (SCALE) v *= 1.0f / (norms[rowid[g]] + 1e-6f);
            if (ADDINIT) v += initv[(size_t)rbase[g] + c];
            out[(size_t)rbase[g] + c] = v;
        }
    }
}

// ---------------------------------------------------------------------------
// logits = gin @ ad_W2[blk] + ad_b2[blk]; argmax -> idx[row]
// optional: state = t + ramp*init; norms = ||state||
// grid 512, NT=64
template <bool UPDATE, bool FIXED0>
__global__ __launch_bounds__(64) void k_small(
    const float* __restrict__ gin, const float* __restrict__ W2,
    const float* __restrict__ b2, int* __restrict__ idx,
    const float* __restrict__ tin, const float* __restrict__ initv,
    float* __restrict__ state, float* __restrict__ norms, float ramp)
{
    const int row = blockIdx.x;
    const int t   = threadIdx.x;
    const int blk = FIXED0 ? 0 : idx[row];
    const int o   = t & 15;
    const int p   = t >> 4;   // 0..3

    float acc = 0.f;
    const float* w2 = W2 + (size_t)blk * E * ABSZ;
    const float* gr = gin + (size_t)row * E;
    for (int e = p; e < E; e += 4)
        acc = fmaf(gr[e], w2[(size_t)e * ABSZ + o], acc);
    acc += __shfl_down(acc, 32, 64);
    acc += __shfl_down(acc, 16, 64);

    __shared__ float s_logits[ABSZ];
    if (t < ABSZ) s_logits[t] = acc + b2[(size_t)blk * ABSZ + t];

    float ss = 0.f;
    if (UPDATE) {
        const float4 tv0 = *reinterpret_cast<const float4*>(tin  + (size_t)row * E + t * 8);
        const float4 tv1 = *reinterpret_cast<const float4*>(tin  + (size_t)row * E + t * 8 + 4);
        const float4 iv0 = *reinterpret_cast<const float4*>(initv + (size_t)row * E + t * 8);
        const float4 iv1 = *reinterpret_cast<const float4*>(initv + (size_t)row * E + t * 8 + 4);
        float4 n0, n1;
        n0.x = tv0.x + ramp * iv0.x;  n0.y = tv0.y + ramp * iv0.y;
        n0.z = tv0.z + ramp * iv0.z;  n0.w = tv0.w + ramp * iv0.w;
        n1.x = tv1.x + ramp * iv1.x;  n1.y = tv1.y + ramp * iv1.y;
        n1.z = tv1.z + ramp * iv1.z;  n1.w = tv1.w + ramp * iv1.w;
        *reinterpret_cast<float4*>(state + (size_t)row * E + t * 8)     = n0;
        *reinterpret_cast<float4*>(state + (size_t)row * E + t * 8 + 4) = n1;
        ss = n0.x*n0.x + n0.y*n0.y + n0.z*n0.z + n0.w*n0.w
           + n1.x*n1.x + n1.y*n1.y + n1.z*n1.z + n1.w*n1.w;
        #pragma unroll
        for (int off2 = 32; off2 > 0; off2 >>= 1) ss += __shfl_down(ss, off2, 64);
    }

    __syncthreads();
    if (t == 0) {
        int a0 = 0, a1 = 0;
        float m0 = s_logits[0], m1 = s_logits[8];
        #pragma unroll
        for (int k = 1; k < 8; ++k) {
            if (s_logits[k]     > m0) { m0 = s_logits[k];     a0 = k; }
            if (s_logits[8 + k] > m1) { m1 = s_logits[8 + k]; a1 = k; }
        }
        idx[row] = a0 * 8 + a1;
        if (UPDATE) norms[row] = sqrtf(ss);
    }
}

// ---------------------------------------------------------------------------
// out = h @ out_W2 + out_b2    grid 64, NT=128
__global__ __launch_bounds__(128) void k_out(
    const float* __restrict__ h, const float* __restrict__ W,
    const float* __restrict__ bias, float* __restrict__ out)
{
    const int c  = threadIdx.x;   // 0..127
    const int r0 = blockIdx.x * 8;
    float acc[8] = {0,0,0,0,0,0,0,0};
    for (int e = 0; e < E; e += 4) {
        const float w0 = W[(size_t)(e + 0) * NC + c];
        const float w1 = W[(size_t)(e + 1) * NC + c];
        const float w2 = W[(size_t)(e + 2) * NC + c];
        const float w3 = W[(size_t)(e + 3) * NC + c];
        #pragma unroll
        for (int g = 0; g < 8; ++g) {
            const float4 hv = *reinterpret_cast<const float4*>(
                h + (size_t)(r0 + g) * E + e);
            acc[g] = fmaf(hv.x, w0, acc[g]);
            acc[g] = fmaf(hv.y, w1, acc[g]);
            acc[g] = fmaf(hv.z, w2, acc[g]);
            acc[g] = fmaf(hv.w, w3, acc[g]);
        }
    }
    const float bv = bias[c];
    #pragma unroll
    for (int g = 0; g < 8; ++g)
        out[(size_t)(r0 + g) * NC + c] = acc[g] + bv;
}

}  // namespace

extern "C" void kernel_launch(void* const* d_in, const int* in_sizes, int n_in,
                              void* d_out, int out_size, void* d_ws, size_t ws_size,
                              hipStream_t stream)
{
    const float* x      = (const float*)d_in[0];
    const float* emb_W  = (const float*)d_in[1];
    const float* emb_b  = (const float*)d_in[2];
    const float* st_W1  = (const float*)d_in[3];
    const float* st_b1  = (const float*)d_in[4];
    const float* st_W2  = (const float*)d_in[5];
    const float* st_b2  = (const float*)d_in[6];
    const float* ad_W1  = (const float*)d_in[7];
    const float* ad_b1  = (const float*)d_in[8];
    const float* ad_W2  = (const float*)d_in[9];
    const float* ad_b2  = (const float*)d_in[10];
    const float* out_W1 = (const float*)d_in[11];
    const float* out_b1 = (const float*)d_in[12];
    const float* out_W2 = (const float*)d_in[13];
    const float* out_b2 = (const float*)d_in[14];
    float* out = (float*)d_out;

    float* ws    = (float*)d_ws;
    float* state = ws;                    // 512*512
    float* initv = ws + 1 * 262144;
    float* tbuf  = ws + 2 * 262144;
    float* hbuf  = ws + 3 * 262144;
    float* norms = ws + 4 * 262144;       // 512
    int*   idx         = (int*)(norms + 512);
    int*   rows_sorted = idx + 512;
    int4*  desc        = (int4*)(rows_sorted + 512);   // 128 int4, 16B aligned
    int*   rows_id     = (int*)(desc + MAXTIL);
    int4*  desc_id     = (int4*)(rows_id + 512);

    const dim3 mv_grid(MAXTIL, 2);

    // setup
    hipLaunchKernelGGL(k_iddesc, dim3(1), dim3(512), 0, stream, rows_id, desc_id);
    hipLaunchKernelGGL(k_embed, dim3(64, 2), dim3(256), 0, stream,
                       x, emb_W, emb_b, state, initv);
    hipLaunchKernelGGL(k_norm, dim3(B), dim3(64), 0, stream, state, norms);

    // initial address: block 0 for all rows, input = initial_state
    hipLaunchKernelGGL((k_mv<true, false, false>), mv_grid, dim3(256), 0, stream,
                       state, hbuf, ad_W1, ad_b1, desc_id, rows_id, norms, initv);
    hipLaunchKernelGGL((k_small<false, true>), dim3(B), dim3(64), 0, stream,
                       hbuf, ad_W2, ad_b2, idx, tbuf, initv, state, norms, 0.f);

    // jump loop
    for (int i = 0; i < J; ++i) {
        const float ramp = (float)i * (1.0f / 6.0f);
        hipLaunchKernelGGL(k_bucket, dim3(1), dim3(512), 0, stream,
                           idx, rows_sorted, desc);
        hipLaunchKernelGGL((k_mv<true, false, false>), mv_grid, dim3(256), 0, stream,
                           state, hbuf, st_W1, st_b1, desc, rows_sorted, norms, initv);
        hipLaunchKernelGGL((k_mv<true, true, false>), mv_grid, dim3(256), 0, stream,
                           hbuf, tbuf, st_W2, st_b2, desc, rows_sorted, norms, initv);
        hipLaunchKernelGGL((k_mv<true, false, false>), mv_grid, dim3(256), 0, stream,
                           tbuf, hbuf, ad_W1, ad_b1, desc, rows_sorted, norms, initv);
        hipLaunchKernelGGL((k_small<true, false>), dim3(B), dim3(64), 0, stream,
                           hbuf, ad_W2, ad_b2, idx, tbuf, initv, state, norms, ramp);
    }

    // final block + output head
    hipLaunchKernelGGL(k_bucket, dim3(1), dim3(512), 0, stream,
                       idx, rows_sorted, desc);
    hipLaunchKernelGGL((k_mv<true, false, false>), mv_grid, dim3(256), 0, stream,
                       state, hbuf, st_W1, st_b1, desc, rows_sorted, norms, initv);
    // final = relu(h @ W2 + b2)/norm + init   -> overwrite state
    hipLaunchKernelGGL((k_mv<true, true, true>), mv_grid, dim3(256), 0, stream,
                       hbuf, state, st_W2, st_b2, desc, rows_sorted, norms, initv);
    // h = relu(final @ out_W1 + out_b1)  (shared weights -> identity desc, blk 0)
    hipLaunchKernelGGL((k_mv<true, false, false>), mv_grid, dim3(256), 0, stream,
                       state, hbuf, out_W1, out_b1, desc_id, rows_id, norms, initv);
    hipLaunchKernelGGL(k_out, dim3(64), dim3(128), 0, stream,
                       hbuf, out_W2, out_b2, out);
}